// Round 7
// baseline (913.796 us; speedup 1.0000x reference)
//
#include <hip/hip_runtime.h>

typedef unsigned short u16;
typedef __attribute__((ext_vector_type(8))) short short8;
typedef __attribute__((ext_vector_type(4))) short s16x4;
typedef __attribute__((ext_vector_type(4))) float floatx4;
typedef __attribute__((ext_vector_type(4))) unsigned short u16x4;

#define NTOK 8192
#define DMODEL 512
#define DFF 2048
#define LSEQ 2048
#define RMARGIN 1e-3f

__device__ __forceinline__ u16 f2bf(float f) {
    union { float f; unsigned u; } x; x.f = f;
    unsigned r = (x.u + 0x7fffu + ((x.u >> 16) & 1u)) >> 16;
    return (u16)r;
}
__device__ __forceinline__ float bf2f(u16 h) {
    union { unsigned u; float f; } x; x.u = ((unsigned)h) << 16;
    return x.f;
}

__device__ __forceinline__ float geluf(float x) {
    return 0.5f * x * (1.0f + erff(x * 0.70710678118654752f));
}

__device__ __forceinline__ void gload_lds16(const void* g, void* l) {
    __builtin_amdgcn_global_load_lds(
        (const __attribute__((address_space(1))) void*)g,
        (__attribute__((address_space(3))) void*)l,
        16, 0, 0);
}

// pack 4 f32 -> 4 bf16 (truncation; fine for P in [0,16])
__device__ __forceinline__ s16x4 pack_p(float p0, float p1, float p2, float p3) {
    union { float f; unsigned u; } a{p0}, b{p1}, c{p2}, d{p3};
    union { unsigned u[2]; s16x4 s; } r;
    r.u[0] = (a.u >> 16) | (b.u & 0xffff0000u);
    r.u[1] = (c.u >> 16) | (d.u & 0xffff0000u);
    return r.s;
}

// ---------------------------------------------------------------------------
// Weight f32 -> bf16 conversion (Wqkv | Wo | W1 | W2 packed)
// ---------------------------------------------------------------------------
__global__ __launch_bounds__(256) void cvt_w(const float* __restrict__ wq,
                                             const float* __restrict__ wo,
                                             const float* __restrict__ w1,
                                             const float* __restrict__ w2,
                                             u16* __restrict__ out) {
    int i = blockIdx.x * 256 + threadIdx.x;
    float v;
    if (i < 786432)       v = wq[i];
    else if (i < 1048576) v = wo[i - 786432];
    else if (i < 2097152) v = w1[i - 1048576];
    else                  v = w2[i - 2097152];
    out[i] = f2bf(v);
}

__global__ __launch_bounds__(256) void copy_f32(const float* __restrict__ a,
                                                float* __restrict__ b) {
    size_t i = ((size_t)blockIdx.x * 256 + threadIdx.x) * 4;
    *(floatx4*)&b[i] = *(const floatx4*)&a[i];
}

// ---------------------------------------------------------------------------
// Rw1 split: B' row n (len 1536) = [hi | hi | lo] of Rw1[n][:]
// ---------------------------------------------------------------------------
__global__ __launch_bounds__(256) void cvt_rw1(const float* __restrict__ Rw1,
                                               u16* __restrict__ out) {
    const int i = blockIdx.x * 256 + threadIdx.x;  // 262144
    const int n = i >> 9, k = i & 511;
    const float v = Rw1[i];
    const u16 hi = f2bf(v);
    const u16 lo = f2bf(v - bf2f(hi));
    out[(size_t)n * 1536 + k] = hi;
    out[(size_t)n * 1536 + 512 + k] = hi;
    out[(size_t)n * 1536 + 1024 + k] = lo;
}

// ---------------------------------------------------------------------------
// rh split: A' row t (len 1536) = [hi | lo | hi] of rh[t][:]. Also zeroes cnt.
// ---------------------------------------------------------------------------
__global__ __launch_bounds__(256) void cvt_split(const float* __restrict__ x,
                                                 u16* __restrict__ out,
                                                 int* __restrict__ cnt) {
    if (blockIdx.x == 0 && threadIdx.x == 0) *cnt = 0;
    const int i = blockIdx.x * 256 + threadIdx.x;  // 1048576 quads
    const int base = i * 4;
    const int row = base >> 9, k = base & 511;
    const floatx4 v = *(const floatx4*)&x[base];
    u16x4 h, l;
#pragma unroll
    for (int e = 0; e < 4; ++e) {
        h[e] = f2bf(v[e]);
        l[e] = f2bf(v[e] - bf2f(h[e]));
    }
    u16* o = out + (size_t)row * 1536;
    *(u16x4*)&o[k] = h;
    *(u16x4*)&o[512 + k] = l;
    *(u16x4*)&o[1024 + k] = h;
}

// ---------------------------------------------------------------------------
// LayerNorm over D=512, one wave per row.
// ---------------------------------------------------------------------------
template<bool OUTF32>
__global__ __launch_bounds__(256)
void ln_k(const float* __restrict__ x, const float* __restrict__ g,
          const float* __restrict__ bb, void* __restrict__ outp) {
    const int row = blockIdx.x * 4 + (threadIdx.x >> 6);
    const int lane = threadIdx.x & 63;
    const float* xr = x + (size_t)row * DMODEL;
    const int c0 = lane * 4, c1 = c0 + 256;
    floatx4 a = *(const floatx4*)&xr[c0];
    floatx4 b = *(const floatx4*)&xr[c1];
    float s = 0.f, sq = 0.f;
#pragma unroll
    for (int e = 0; e < 4; ++e) { s += a[e]; sq += a[e] * a[e]; }
#pragma unroll
    for (int e = 0; e < 4; ++e) { s += b[e]; sq += b[e] * b[e]; }
#pragma unroll
    for (int m = 32; m >= 1; m >>= 1) {
        s += __shfl_xor(s, m);
        sq += __shfl_xor(sq, m);
    }
    const float mean = s * (1.f / 512.f);
    const float rstd = rsqrtf(sq * (1.f / 512.f) - mean * mean + 1e-5f);
    floatx4 g0 = *(const floatx4*)&g[c0];
    floatx4 g1 = *(const floatx4*)&g[c1];
    floatx4 b0 = *(const floatx4*)&bb[c0];
    floatx4 b1 = *(const floatx4*)&bb[c1];
    floatx4 y0, y1;
#pragma unroll
    for (int e = 0; e < 4; ++e) {
        y0[e] = (a[e] - mean) * rstd * g0[e] + b0[e];
        y1[e] = (b[e] - mean) * rstd * g1[e] + b1[e];
    }
    if (OUTF32) {
        float* o = (float*)outp + (size_t)row * DMODEL;
        *(floatx4*)&o[c0] = y0;
        *(floatx4*)&o[c1] = y1;
    } else {
        u16* o = (u16*)outp + (size_t)row * DMODEL;
        u16x4 p0, p1;
#pragma unroll
        for (int e = 0; e < 4; ++e) { p0[e] = f2bf(y0[e]); p1[e] = f2bf(y1[e]); }
        *(u16x4*)&o[c0] = p0;
        *(u16x4*)&o[c1] = p1;
    }
}

// ---------------------------------------------------------------------------
// bf16 MFMA GEMM: C[M,N] = epi(A[M,K] @ Bw[N,K]^T + bias)
// EPI: 0 = QKV epilogue (Q scaled, V transposed to Cv)
//      1 = bf16 gelu out
//      2 = f32 out = res + v
//      3 = f32 out = keep ? res + v : old   (keep = depth[row] >= aux)
//      4 = f32 out = gelu(v)      (router pass-1)
// ---------------------------------------------------------------------------
template<int EPI, int BN>
__global__ __launch_bounds__(256, 2)
void gemm_bt(const u16* __restrict__ A, const u16* __restrict__ Bw,
             const float* __restrict__ bias,
             u16* __restrict__ Cb, float* __restrict__ Cf,
             const float* __restrict__ res, const float* __restrict__ depth,
             u16* __restrict__ Cv,
             float aux, int N, int K) {
    constexpr int NJ = BN / 32;
    __shared__ __align__(16) u16 As[128 * 32];
    __shared__ __align__(16) u16 Bs[BN * 32];
    const int tid = threadIdx.x;
    const int lane = tid & 63;
    const int w = tid >> 6;
    const int wm = (w >> 1) * 64;
    const int wn = (w & 1) * (BN / 2);
    const int mBase = blockIdx.x * 128;
    const int nBase = blockIdx.y * BN;
    const int q4 = lane >> 4, rl = lane & 15;

    floatx4 acc[4][NJ];
#pragma unroll
    for (int i = 0; i < 4; ++i)
#pragma unroll
        for (int j = 0; j < NJ; ++j) acc[i][j] = (floatx4){0.f, 0.f, 0.f, 0.f};

    const int i0 = tid, i1 = tid + 256;
    const int ar0 = i0 >> 2, ac0 = ((i0 & 3) ^ ((i0 >> 3) & 3)) * 8;
    const int ar1 = i1 >> 2, ac1 = ((i1 & 3) ^ ((i1 >> 3) & 3)) * 8;
    const u16* pA0 = A + (size_t)(mBase + ar0) * K + ac0;
    const u16* pA1 = A + (size_t)(mBase + ar1) * K + ac1;
    const u16* pB0 = Bw + (size_t)(nBase + ar0) * K + ac0;
    const u16* pB1 = (BN == 128) ? Bw + (size_t)(nBase + ar1) * K + ac1 : pB0;
    u16* lA0 = &As[i0 * 8];
    u16* lA1 = &As[i1 * 8];
    u16* lB0 = &Bs[i0 * 8];
    u16* lB1 = (BN == 128) ? &Bs[i1 * 8] : lB0;

    for (int k0 = 0; k0 < K; k0 += 32) {
        gload_lds16(pA0, lA0);
        gload_lds16(pA1, lA1);
        gload_lds16(pB0, lB0);
        if (BN == 128) gload_lds16(pB1, lB1);
        pA0 += 32; pA1 += 32; pB0 += 32;
        if (BN == 128) pB1 += 32;
        __syncthreads();
        short8 af[4], bf[NJ];
#pragma unroll
        for (int t = 0; t < 4; ++t) {
            const int r = wm + t * 16 + rl;
            af[t] = *(const short8*)&As[r * 32 + (q4 ^ ((r >> 1) & 3)) * 8];
        }
#pragma unroll
        for (int t = 0; t < NJ; ++t) {
            const int r = wn + t * 16 + rl;
            bf[t] = *(const short8*)&Bs[r * 32 + (q4 ^ ((r >> 1) & 3)) * 8];
        }
#pragma unroll
        for (int ti = 0; ti < 4; ++ti)
#pragma unroll
            for (int tj = 0; tj < NJ; ++tj)
                acc[ti][tj] = __builtin_amdgcn_mfma_f32_16x16x32_bf16(
                    af[ti], bf[tj], acc[ti][tj], 0, 0, 0);
        __syncthreads();
    }

#pragma unroll
    for (int ti = 0; ti < 4; ++ti) {
        const int r0 = mBase + wm + ti * 16 + q4 * 4;
#pragma unroll
        for (int tj = 0; tj < NJ; ++tj) {
            const int c = nBase + wn + tj * 16 + rl;
            const float bv = bias[c];
            if (EPI == 0) {
                if (nBase < 1024) {
                    const float sc = (nBase < 512) ? aux : 1.0f;
#pragma unroll
                    for (int rr = 0; rr < 4; ++rr)
                        Cb[(size_t)(r0 + rr) * 1024 + c] =
                            f2bf((acc[ti][tj][rr] + bv) * sc);
                } else {
                    const int cm = c - 1024;
                    const int hh = cm >> 6, dh = cm & 63;
                    const int bb2 = r0 >> 11, kv = r0 & 2047;
                    u16x4 pk;
#pragma unroll
                    for (int rr = 0; rr < 4; ++rr)
                        pk[rr] = f2bf(acc[ti][tj][rr] + bv);
                    *(u16x4*)&Cv[((size_t)(bb2 * 8 + hh) * 64 + dh) * 2048 + kv] = pk;
                }
            } else {
#pragma unroll
                for (int rr = 0; rr < 4; ++rr) {
                    const int r = r0 + rr;
                    const float v = acc[ti][tj][rr] + bv;
                    if (EPI == 1) {
                        Cb[(size_t)r * N + c] = f2bf(geluf(v));
                    } else if (EPI == 2) {
                        Cf[(size_t)r * N + c] = res[(size_t)r * N + c] + v;
                    } else if (EPI == 3) {
                        if (depth[r] >= aux)
                            Cf[(size_t)r * N + c] = res[(size_t)r * N + c] + v;
                    } else {
                        Cf[(size_t)r * N + c] = geluf(v);
                    }
                }
            }
        }
    }
}

// ---------------------------------------------------------------------------
// Flash attention via S^T (register-resident P^T). 128 q-rows/block,
// 32 q-rows per wave (nt=2): K/V LDS reads amortized over 2x q-rows.
// All hot-loop LDS addresses are mt/dt-invariant bases + immediate offsets.
// ---------------------------------------------------------------------------
__global__ __launch_bounds__(256, 2)
void attn_k(const u16* __restrict__ qk, const u16* __restrict__ vT,
            u16* __restrict__ o) {
    const int qt = blockIdx.x;
    const int bh = blockIdx.y;
    const int b = bh >> 3, h = bh & 7;
    const int tid = threadIdx.x, lane = tid & 63, w = tid >> 6;
    const int tok0 = b * LSEQ;
    const int qrow0 = qt * 128 + w * 32;
    const int q4 = lane >> 4, rl = lane & 15;

    __shared__ __align__(16) u16 Kt[128 * 64];   // [kv][dh], chunk-swizzled
    __shared__ __align__(16) u16 Vt[64 * 128];   // [dh][kv], chunk-swizzled

    const u16* vbase = vT + (size_t)bh * 64 * 2048;

    short8 qf[2][2];
#pragma unroll
    for (int nt = 0; nt < 2; ++nt)
#pragma unroll
        for (int ks = 0; ks < 2; ++ks)
            qf[nt][ks] = *(const short8*)&qk[(size_t)(tok0 + qrow0 + nt * 16 + rl) * 1024
                                             + h * 64 + ks * 32 + q4 * 8];

    floatx4 oacc[4][2];
#pragma unroll
    for (int dt = 0; dt < 4; ++dt)
#pragma unroll
        for (int nt = 0; nt < 2; ++nt) oacc[dt][nt] = (floatx4){0.f, 0.f, 0.f, 0.f};
    float lsum[2] = {0.f, 0.f};

    // mt-invariant K read bases (r&7 == rl&7 since mt*16 % 8 == 0)
    const u16* kp0 = &Kt[rl * 64 + ((q4 ^ (rl & 7))) * 8];
    const u16* kp1 = &Kt[rl * 64 + (((4 + q4) ^ (rl & 7))) * 8];

    for (int kt = 0; kt < 16; ++kt) {
        const int kv0 = kt * 128;
        __syncthreads();
        // K [128 kv][64 dh]: slot i -> (r=i>>3, chunk (i&7)^(r&7))
#pragma unroll
        for (int it = 0; it < 4; ++it) {
            const int i = it * 256 + tid;
            const int r = i >> 3;
            const int c = ((i & 7) ^ (r & 7)) * 8;
            gload_lds16(&qk[(size_t)(tok0 + kv0 + r) * 1024 + 512 + h * 64 + c],
                        &Kt[i * 8]);
        }
        // V^T [64 dh][128 kv]: slot i -> (dh=i>>4, chunk (i&15)^(dh&15))
#pragma unroll
        for (int it = 0; it < 4; ++it) {
            const int i = it * 256 + tid;
            const int dh = i >> 4;
            const int ch = (i & 15) ^ (dh & 15);
            gload_lds16(&vbase[(size_t)dh * 2048 + kv0 + ch * 8], &Vt[i * 8]);
        }
        __syncthreads();

#pragma unroll
        for (int mt = 0; mt < 8; ++mt) {
            const short8 kf0 = *(const short8*)&kp0[mt * 1024];
            const short8 kf1 = *(const short8*)&kp1[mt * 1024];
            floatx4 s[2];
#pragma unroll
            for (int nt = 0; nt < 2; ++nt) {
                s[nt] = __builtin_amdgcn_mfma_f32_16x16x32_bf16(kf0, qf[nt][0],
                        (floatx4){0.f, 0.f, 0.f, 0.f}, 0, 0, 0);
                s[nt] = __builtin_amdgcn_mfma_f32_16x16x32_bf16(kf1, qf[nt][1],
                        s[nt], 0, 0, 0);
            }
            s16x4 pb[2];
#pragma unroll
            for (int nt = 0; nt < 2; ++nt) {
                const float p0 = exp2f(s[nt][0]);
                const float p1 = exp2f(s[nt][1]);
                const float p2 = exp2f(s[nt][2]);
                const float p3 = exp2f(s[nt][3]);
                lsum[nt] += (p0 + p1) + (p2 + p3);
                pb[nt] = pack_p(p0, p1, p2, p3);
            }
            const int ct = 2 * mt + (q4 >> 1);
            const u16* vp = &Vt[(ct ^ rl) * 8 + (q4 & 1) * 4 + rl * 128];
#pragma unroll
            for (int dt = 0; dt < 4; ++dt) {
                const s16x4 vf = *(const s16x4*)&vp[dt * 2048];
#pragma unroll
                for (int nt = 0; nt < 2; ++nt)
                    oacc[dt][nt] = __builtin_amdgcn_mfma_f32_16x16x16bf16_1k(
                        vf, pb[nt], oacc[dt][nt], 0, 0, 0);
            }
        }
    }

#pragma unroll
    for (int nt = 0; nt < 2; ++nt) {
        float l = lsum[nt];
        l += __shfl_xor(l, 16);
        l += __shfl_xor(l, 32);
        const float inv = 1.0f / l;
        const size_t row = tok0 + qrow0 + nt * 16 + rl;
#pragma unroll
        for (int dt = 0; dt < 4; ++dt) {
            u16x4 pk;
#pragma unroll
            for (int rr = 0; rr < 4; ++rr) pk[rr] = f2bf(oacc[dt][nt][rr] * inv);
            *(u16x4*)&o[row * DMODEL + h * 64 + dt * 16 + q4 * 4] = pk;
        }
    }
}

// ---------------------------------------------------------------------------
// Router logits pass-1 (f32, from split-bf16 GEMM rr): one wave per token.
// Flags tokens whose top-2 gap < RMARGIN for exact f64 recheck.
// ---------------------------------------------------------------------------
__global__ __launch_bounds__(256)
void router_logits_f32(const float* __restrict__ rr, const float* __restrict__ Rw2,
                       const float* __restrict__ Rb2, float* __restrict__ logits,
                       float* __restrict__ depthf, int* __restrict__ cnt,
                       int* __restrict__ list) {
    const int t = blockIdx.x * 4 + (threadIdx.x >> 6);
    const int lane = threadIdx.x & 63;
    const float* xr = rr + (size_t)t * 512;
    const int c0 = lane * 4, c1 = c0 + 256;
    floatx4 a = *(const floatx4*)&xr[c0];
    floatx4 b = *(const floatx4*)&xr[c1];
    float s[4];
#pragma unroll
    for (int d = 0; d < 4; ++d) {
        const float* wr = Rw2 + d * 512;
        floatx4 wa = *(const floatx4*)&wr[c0];
        floatx4 wb = *(const floatx4*)&wr[c1];
        float acc = 0.f;
#pragma unroll
        for (int e = 0; e < 4; ++e) acc += a[e] * wa[e];
#pragma unroll
        for (int e = 0; e < 4; ++e) acc += b[e] * wb[e];
        s[d] = acc;
    }
#pragma unroll
    for (int m = 32; m >= 1; m >>= 1)
#pragma unroll
        for (int d = 0; d < 4; ++d) s[d] += __shfl_xor(s[d], m);
    if (lane == 0) {
        float v[4];
        float bv = -1e30f; int best = 0;
#pragma unroll
        for (int d = 0; d < 4; ++d) {
            v[d] = s[d] + Rb2[d];
            logits[(size_t)t * 4 + d] = v[d];
            if (v[d] > bv) { bv = v[d]; best = d; }
        }
        float second = -1e30f;
#pragma unroll
        for (int d = 0; d < 4; ++d)
            if (d != best) second = fmaxf(second, v[d]);
        depthf[t] = (float)(best + 1);
        if (bv - second < RMARGIN) {
            int idx = atomicAdd(cnt, 1);
            list[idx] = t;
        }
    }
}

// ---------------------------------------------------------------------------
// Exact f64 router recheck for flagged tokens (gather).
// ---------------------------------------------------------------------------
__global__ __launch_bounds__(256)
void router_exact(const float* __restrict__ rh, const float* __restrict__ Rw1,
                  const float* __restrict__ Rb1, const float* __restrict__ Rw2,
                  const float* __restrict__ Rb2, const int* __restrict__ cnt,
                  const int* __restrict__ list, float* __restrict__ logits,
                  float* __restrict__ depthf) {
    __shared__ float rhs[512];
    __shared__ double rrd[512];
    __shared__ double lg[4];
    const int n = *cnt;
    const int tid = threadIdx.x;
    for (int ii = blockIdx.x; ii < n; ii += gridDim.x) {
        const int t = list[ii];
        rhs[tid] = rh[(size_t)t * 512 + tid];
        rhs[tid + 256] = rh[(size_t)t * 512 + 256 + tid];
        __syncthreads();
#pragma unroll
        for (int oo = 0; oo < 2; ++oo) {
            const int nn = tid + oo * 256;
            double acc = (double)Rb1[nn];
            const float* wrow = Rw1 + (size_t)nn * 512;
            for (int k = 0; k < 512; ++k)
                acc = fma((double)rhs[k], (double)wrow[k], acc);
            rrd[nn] = 0.5 * acc * (1.0 + erf(acc * 0.70710678118654752440));
        }
        __syncthreads();
        const int w = tid >> 6, lane = tid & 63;
        double acc2 = 0.0;
        for (int k = lane; k < 512; k += 64)
            acc2 += rrd[k] * (double)Rw2[w * 512 + k];
#pragma unroll
        for (int m = 32; m >= 1; m >>= 1) acc2 += __shfl_xor(acc2, m);
        if (lane == 0) lg[w] = acc2 + (double)Rb2[w];
        __syncthreads();
        if (tid == 0) {
            double bv = -1e300; int best = 0;
#pragma unroll
            for (int d = 0; d < 4; ++d) {
                const double v = lg[d];
                logits[(size_t)t * 4 + d] = (float)v;
                if (v > bv) { bv = v; best = d; }
            }
            depthf[t] = (float)(best + 1);
        }
        __syncthreads();
    }
}

// ---------------------------------------------------------------------------
// Host launcher
// ---------------------------------------------------------------------------
extern "C" void kernel_launch(void* const* d_in, const int* in_sizes, int n_in,
                              void* d_out, int out_size, void* d_ws, size_t ws_size,
                              hipStream_t stream) {
    (void)in_sizes; (void)n_in; (void)out_size; (void)ws_size;
    const float* x    = (const float*)d_in[0];
    const float* ln1g = (const float*)d_in[1];
    const float* ln1b = (const float*)d_in[2];
    const float* Wqkv = (const float*)d_in[3];
    const float* bqkv = (const float*)d_in[4];
    const float* Wo   = (const float*)d_in[5];
    const float* bo   = (const float*)d_in[6];
    const float* ln2g = (const float*)d_in[7];
    const float* ln2b = (const float*)d_in[8];
    const float* W1   = (const float*)d_in[9];
    const float* b1   = (const float*)d_in[10];
    const float* W2   = (const float*)d_in[11];
    const float* b2   = (const float*)d_in[12];
    const float* rng  = (const float*)d_in[13];
    const float* rnb  = (const float*)d_in[14];
    const float* Rw1  = (const float*)d_in[15];
    const float* Rb1  = (const float*)d_in[16];
    const float* Rw2  = (const float*)d_in[17];
    const float* Rb2  = (const float*)d_in[18];

    float* cur    = (float*)d_out;
    float* depthf = cur + (size_t)NTOK * DMODEL;
    float* logits = depthf + NTOK;

    char* ws = (char*)d_ws;
    float* xmid = (float*)ws;                       // 16 MB f32          @ 0
    u16* sbuf   = (u16*)(ws + 16777216);            //  8 MB bf16         @ 16M
    u16* qk     = (u16*)(ws + 25165824);            // 16 MB bf16 (Q|K)   @ 24M
    u16* ffb    = (u16*)(ws + 41943040);            // 32 MB bf16         @ 40M
    u16* vTb    = (u16*)(ws + 75497472);            //  8 MB bf16 V^T     @ 72M
    u16* wbf    = (u16*)(ws + 83886080);            //  6 MB bf16 weights @ 80M

    // router-phase aliases (all dead before the level loop runs)
    u16* rw1s   = (u16*)(ws + 16777216);            // 1.5 MB B' split    @ 16M (sbuf)
    int* rcnt   = (int*)(ws + 18874368);            // counter            @ 18M
    int* rlist  = rcnt + 16;                        // flagged tokens
    u16* asplit = ffb;                              // 25.2 MB A' split   @ 40M
    float* rrf  = (float*)qk;                       // 16 MB rr f32       @ 24M

    u16* wq = wbf;
    u16* wo = wbf + 786432;
    u16* w1 = wbf + 1048576;
    u16* w2 = wbf + 2097152;

    const float qsc = 0.125f * 1.4426950408889634f;  // (1/sqrt(dh)) * log2(e)

    cvt_w<<<12288, 256, 0, stream>>>(Wqkv, Wo, W1, W2, wbf);
    copy_f32<<<4096, 256, 0, stream>>>(x, cur);

    // --- router: split-bf16 pass-1 + exact f64 recheck of near-ties ---
    ln_k<true><<<2048, 256, 0, stream>>>(x, rng, rnb, xmid);
    cvt_rw1<<<1024, 256, 0, stream>>>(Rw1, rw1s);
    cvt_split<<<4096, 256, 0, stream>>>(xmid, asplit, rcnt);
    gemm_bt<4, 64><<<dim3(64, 8), 256, 0, stream>>>(
        asplit, rw1s, Rb1, nullptr, rrf, nullptr, nullptr, nullptr, 0.f, 512, 1536);
    router_logits_f32<<<2048, 256, 0, stream>>>(rrf, Rw2, Rb2, logits, depthf,
                                                rcnt, rlist);
    router_exact<<<128, 256, 0, stream>>>(xmid, Rw1, Rb1, Rw2, Rb2, rcnt, rlist,
                                          logits, depthf);

    // --- 4 recursion levels ---
    for (int level = 1; level <= 4; ++level) {
        ln_k<false><<<2048, 256, 0, stream>>>(cur, ln1g, ln1b, sbuf);
        gemm_bt<0, 128><<<dim3(64, 12), 256, 0, stream>>>(
            sbuf, wq, bqkv, qk, nullptr, nullptr, nullptr, vTb, qsc, 1536, 512);
        attn_k<<<dim3(16, 32), 256, 0, stream>>>(qk, vTb, sbuf);
        gemm_bt<2, 64><<<dim3(64, 8), 256, 0, stream>>>(
            sbuf, wo, bo, nullptr, xmid, cur, nullptr, nullptr, 0.f, 512, 512);
        ln_k<false><<<2048, 256, 0, stream>>>(xmid, ln2g, ln2b, sbuf);
        gemm_bt<1, 128><<<dim3(64, 16), 256, 0, stream>>>(
            sbuf, w1, b1, ffb, nullptr, nullptr, nullptr, nullptr, 0.f, 2048, 512);
        gemm_bt<3, 64><<<dim3(64, 8), 256, 0, stream>>>(
            ffb, w2, b2, nullptr, cur, xmid, depthf, nullptr, (float)level, 512, 2048);
    }
}